// Round 4
// baseline (233.391 us; speedup 1.0000x reference)
//
#include <hip/hip_runtime.h>

#define N_EDGES  800000
#define N_NODES  50000
#define IN_DIM   64
#define EDGE_DIM 32
#define HID      96
#define OUT_DIM  64
#define BE       128              // edges per tile
#define PAD      104              // LDS row length (bf16): 208 B -> 16B-aligned rows, 2-way banks (free)
#define NTILES   (N_EDGES / BE)   // 6250 exactly
#define THREADS  512
#define GRID     512              // 2 blocks/CU, persistent

typedef __attribute__((ext_vector_type(8))) short  short8;
typedef __attribute__((ext_vector_type(4))) ushort bf16x4;   // renamed: ushort4 collides with HIP vector types
typedef __attribute__((ext_vector_type(4))) float  f32x4;

__device__ inline ushort f2bf(float f) {
    union { float f; unsigned u; } v; v.f = f;
    unsigned r = v.u + 0x7FFFu + ((v.u >> 16) & 1u);   // round-to-nearest-even
    return (ushort)(r >> 16);
}

// ---------------------------------------------------------------------------
// Kernel 1: zero output accumulator + counts.
// ---------------------------------------------------------------------------
__global__ __launch_bounds__(256) void zero_kernel(float* __restrict__ out,
                                                   float* __restrict__ cnt) {
    int i = blockIdx.x * 256 + threadIdx.x;
    if (i < N_NODES * OUT_DIM) out[i] = 0.0f;
    if (i < N_NODES) cnt[i] = 0.0f;
}

// ---------------------------------------------------------------------------
// Kernel 2: fused gather -> bf16 MFMA MLP -> atomic scatter.
// 512 threads = 8 waves sharing one LDS weight copy; each wave owns 16
// edge-rows end-to-end -> no __syncthreads in the tile loop (same-wave DS
// ops are in-order; lgkmcnt(0) fences the cross-lane LDS handoffs).
// LDS = 26624 (sA) + 19968 (W1T) + 13312 (W2T) = 59904 B -> 2 blocks/CU,
// 16 waves/CU (4/SIMD), double round-2's occupancy.
// ---------------------------------------------------------------------------
__global__ __launch_bounds__(THREADS, 4) void edge_mlp_mfma_kernel(
    const float* __restrict__ x,
    const int*   __restrict__ ei,     // [2, E] int32
    const float* __restrict__ ea,
    const float* __restrict__ W1,     // [HID, HID] row-major (k, n)
    const float* __restrict__ b1,
    const float* __restrict__ W2,     // [HID, OUT] row-major (k, n)
    const float* __restrict__ b2,
    float*       __restrict__ out,    // [N, OUT] accumulator
    float*       __restrict__ cnt)    // [N]
{
    __shared__ ushort sA[BE][PAD];        // input tile, then H (reused)
    __shared__ ushort sW1T[HID][PAD];     // W1 transposed: [n][k]
    __shared__ ushort sW2T[OUT_DIM][PAD]; // W2 transposed: [n][k]

    const int tid  = threadIdx.x;
    const int wave = tid >> 6;
    const int lane = tid & 63;
    const int lr   = lane & 15;   // frag row/col index
    const int lg   = lane >> 4;   // k-group / row-group
    const int el_base = wave * 16;  // this wave's 16 rows of the tile

    // ---- stage weights (bf16, transposed), float4-vectorized ----
    #pragma unroll 2
    for (int i = tid; i < HID * HID / 4; i += THREADS) {   // 2304 float4s
        float4 v = reinterpret_cast<const float4*>(W1)[i];
        int k = (i * 4) / HID, n = (i * 4) % HID;
        sW1T[n + 0][k] = f2bf(v.x); sW1T[n + 1][k] = f2bf(v.y);
        sW1T[n + 2][k] = f2bf(v.z); sW1T[n + 3][k] = f2bf(v.w);
    }
    #pragma unroll 2
    for (int i = tid; i < HID * OUT_DIM / 4; i += THREADS) {  // 1536 float4s
        float4 v = reinterpret_cast<const float4*>(W2)[i];
        int k = (i * 4) / OUT_DIM, n = (i * 4) % OUT_DIM;
        sW2T[n + 0][k] = f2bf(v.x); sW2T[n + 1][k] = f2bf(v.y);
        sW2T[n + 2][k] = f2bf(v.z); sW2T[n + 3][k] = f2bf(v.w);
    }
    // per-lane bias fragments (replicated across lg groups)
    float rb1[6], rb2[4];
    #pragma unroll
    for (int nt = 0; nt < 6; ++nt) rb1[nt] = b1[nt * 16 + lr];
    #pragma unroll
    for (int nt = 0; nt < 4; ++nt) rb2[nt] = b2[nt * 16 + lr];
    __syncthreads();

    for (int tl = blockIdx.x; tl < NTILES; tl += gridDim.x) {
        const int e0 = tl * BE;

        // ---- gather: 4 lanes per edge, 6 float4 each; wave fills its own rows ----
        {
            const int el   = el_base + (lane >> 2);
            const int part = lane & 3;
            const int e    = e0 + el;
            const int src  = ei[e];
            const float4* xp = reinterpret_cast<const float4*>(x) + (size_t)src * 16;
            const float4* ep = reinterpret_cast<const float4*>(ea) + (size_t)e * 8;
            #pragma unroll
            for (int i = 0; i < 6; ++i) {
                const int f = part + 4 * i;            // 0..23; i<4 -> x, else ea
                float4 v = (i < 4) ? xp[f] : ep[f - 16];
                bf16x4 w = { f2bf(v.x), f2bf(v.y), f2bf(v.z), f2bf(v.w) };
                *(bf16x4*)&sA[el][f * 4] = w;          // 8B aligned (row stride 208B)
            }
            if (part == 0) atomicAdd(cnt + ei[N_EDGES + e], 1.0f);
        }
        asm volatile("s_waitcnt lgkmcnt(0)" ::: "memory");
        __builtin_amdgcn_sched_barrier(0);

        // ---- GEMM1: H = relu(A @ W1 + b1), A = 16 rows x 96 ----
        short8 af[3];
        #pragma unroll
        for (int ks = 0; ks < 3; ++ks)
            af[ks] = *(const short8*)&sA[el_base + lr][ks * 32 + lg * 8];

        f32x4 acc1[6];
        #pragma unroll
        for (int nt = 0; nt < 6; ++nt) {
            float bv = rb1[nt];
            acc1[nt] = f32x4{ bv, bv, bv, bv };
        }
        #pragma unroll
        for (int nt = 0; nt < 6; ++nt) {
            short8 bf[3];
            #pragma unroll
            for (int ks = 0; ks < 3; ++ks)
                bf[ks] = *(const short8*)&sW1T[nt * 16 + lr][ks * 32 + lg * 8];
            #pragma unroll
            for (int ks = 0; ks < 3; ++ks)
                acc1[nt] = __builtin_amdgcn_mfma_f32_16x16x32_bf16(
                    af[ks], bf[ks], acc1[nt], 0, 0, 0);
        }

        // ---- ReLU + write H back over sA (bf16). D layout: col=lr, row=lg*4+j ----
        #pragma unroll
        for (int nt = 0; nt < 6; ++nt)
            #pragma unroll
            for (int j = 0; j < 4; ++j)
                sA[el_base + lg * 4 + j][nt * 16 + lr] =
                    f2bf(fmaxf(acc1[nt][j], 0.0f));
        asm volatile("s_waitcnt lgkmcnt(0)" ::: "memory");
        __builtin_amdgcn_sched_barrier(0);

        // ---- GEMM2: O = H @ W2 + b2 ----
        short8 a2[3];
        #pragma unroll
        for (int ks = 0; ks < 3; ++ks)
            a2[ks] = *(const short8*)&sA[el_base + lr][ks * 32 + lg * 8];

        f32x4 acc2[4];
        #pragma unroll
        for (int nt = 0; nt < 4; ++nt) {
            float bv = rb2[nt];
            acc2[nt] = f32x4{ bv, bv, bv, bv };
        }
        #pragma unroll
        for (int nt = 0; nt < 4; ++nt) {
            short8 bf[3];
            #pragma unroll
            for (int ks = 0; ks < 3; ++ks)
                bf[ks] = *(const short8*)&sW2T[nt * 16 + lr][ks * 32 + lg * 8];
            #pragma unroll
            for (int ks = 0; ks < 3; ++ks)
                acc2[nt] = __builtin_amdgcn_mfma_f32_16x16x32_bf16(
                    a2[ks], bf[ks], acc2[nt], 0, 0, 0);
        }

        // ---- scatter: out[col[e]][o] += acc2 (lane owns rows lg*4+j) ----
        int nd[4];
        #pragma unroll
        for (int j = 0; j < 4; ++j)
            nd[j] = ei[N_EDGES + e0 + el_base + lg * 4 + j];
        #pragma unroll
        for (int nt = 0; nt < 4; ++nt)
            #pragma unroll
            for (int j = 0; j < 4; ++j)
                atomicAdd(out + (size_t)nd[j] * OUT_DIM + nt * 16 + lr,
                          acc2[nt][j]);
    }
}

// ---------------------------------------------------------------------------
// Kernel 3: divide by max(count, 1).
// ---------------------------------------------------------------------------
__global__ __launch_bounds__(256) void div_kernel(float* __restrict__ out,
                                                  const float* __restrict__ cnt) {
    int i = blockIdx.x * 256 + threadIdx.x;
    if (i < N_NODES * OUT_DIM) {
        float c = cnt[i / OUT_DIM];
        out[i] = out[i] / fmaxf(c, 1.0f);
    }
}

extern "C" void kernel_launch(void* const* d_in, const int* in_sizes, int n_in,
                              void* d_out, int out_size, void* d_ws, size_t ws_size,
                              hipStream_t stream) {
    const float* x  = (const float*)d_in[0];
    const int*   ei = (const int*)d_in[1];
    const float* ea = (const float*)d_in[2];
    const float* W1 = (const float*)d_in[3];
    const float* b1 = (const float*)d_in[4];
    const float* W2 = (const float*)d_in[5];
    const float* b2 = (const float*)d_in[6];
    float* out = (float*)d_out;
    float* cnt = (float*)d_ws;  // N_NODES floats

    {
        int blocks = (N_NODES * OUT_DIM + 255) / 256;
        zero_kernel<<<blocks, 256, 0, stream>>>(out, cnt);
    }
    edge_mlp_mfma_kernel<<<GRID, THREADS, 0, stream>>>(x, ei, ea, W1, b1, W2, b2, out, cnt);
    {
        int blocks = (N_NODES * OUT_DIM + 255) / 256;
        div_kernel<<<blocks, 256, 0, stream>>>(out, cnt);
    }
}